// Round 8
// baseline (1140.109 us; speedup 1.0000x reference)
//
#include <hip/hip_runtime.h>
#include <hip/hip_bf16.h>

// LSTM B=256 T=512 H=256 E=6 V=10 C=10. fp32 in/out.
// 16 blocks x 512 threads (8 waves, 2/SIMD). Block owns 16 batch cols; wave w
// owns hidden rows 32w..32w+31 for all 4 gates.
// INT8 path: weights per-row quantized into register-resident i8 MFMA A-frags
// (mfma_i32_16x16x64_i8, exact i32 accum); h quantized at 127, double-buffered
// in LDS, ONE barrier per step.
// ROUND 8: all 5 activations per element via nearest-bin LDS LUTs (4096-entry
// f32 sigma + tanh over [-8,8], bin 1/256) -> zero transcendentals in the hot
// loop (transc wave-inst ~14-16 cyc was ~70% of the act phase).

typedef __attribute__((ext_vector_type(4))) int   int4v;
typedef __attribute__((ext_vector_type(8))) short short8;
typedef __attribute__((ext_vector_type(4))) short short4v;
typedef __attribute__((ext_vector_type(4))) float float4v;

#define MFMA_I8(a, b, c) __builtin_amdgcn_mfma_i32_16x16x64_i8(a, b, c, 0, 0, 0)

__device__ __forceinline__ float b2f(short s) {
    union { unsigned int u; float f; } v; v.u = ((unsigned int)(unsigned short)s) << 16; return v.f;
}
__device__ __forceinline__ short f2b(float f) {
    __hip_bfloat16 b = __float2bfloat16(f); return *(short*)&b;
}
// nearest-bin LUT index for domain [-8,8), 4096 bins: floor((p+8)*256), clamped
__device__ __forceinline__ unsigned lut_idx(float p) {
    float t = fmaf(p, 256.f, 2048.f);
    t = __builtin_amdgcn_fmed3f(t, 0.f, 4095.f);
    return (unsigned)t;   // v_cvt_u32_f32 truncates (t >= 0)
}

__global__ __attribute__((amdgpu_flat_work_group_size(512, 512), amdgpu_waves_per_eu(2, 2)))
void lstm_i8(
    const int* __restrict__ x,
    const float* __restrict__ emb,
    const float* __restrict__ Wxg, const float* __restrict__ Whg, const float* __restrict__ bg,
    const float* __restrict__ Wxi, const float* __restrict__ Whi, const float* __restrict__ bi,
    const float* __restrict__ Wxf, const float* __restrict__ Whf, const float* __restrict__ bff,
    const float* __restrict__ Wxo, const float* __restrict__ Who, const float* __restrict__ bo,
    const float* __restrict__ Wp, const float* __restrict__ bp,
    float* __restrict__ out)
{
    const int tid = threadIdx.x, bid = blockIdx.x;
    const int c0 = bid * 16;
    const int w = tid >> 6, lane = tid & 63;
    const int l = lane & 15, q = lane >> 4;
    const int rw = 32 * w;

    __shared__ __align__(16) unsigned int hbuf[2][16 * 272 / 4];  // h i8 [parity][col][k]
    __shared__ __align__(16) short hfin[16 * 264];                // final h bf16 [col][k]
    __shared__ unsigned char xdig2[512 * 16];                     // [t][col]
    __shared__ __align__(16) short tblL[16 * 720];                // [w2rt][d][q][g*4+i] bf16 (raw Wx@emb)
    __shared__ float scaleL[4 * 256];                             // per-gate per-row max|W|
    __shared__ float lutS[4096];                                  // sigmoid over [-8,8)
    __shared__ float lutT[4096];                                  // tanh    over [-8,8)

    const float* WxT[4] = {Wxg, Wxi, Wxf, Wxo};
    const float* WhT[4] = {Whg, Whi, Whf, Who};

    // ---- init: zero h buf0, stage digits, build activation LUTs ----
    for (int i = tid; i < 16 * 272 / 4; i += 512) hbuf[0][i] = 0u;
    for (int i = tid; i < 8192; i += 512)
        xdig2[i] = (unsigned char)x[(c0 + (i & 15)) * 512 + (i >> 4)];
    for (int i = tid; i < 8192; i += 512) {
        int k = i & 4095;
        float xv = (k + 0.5f) * (1.0f / 256.0f) - 8.0f;   // bin center
        if (i < 4096) lutS[k] = 1.f / (1.f + __expf(-xv));
        else          lutT[k] = 2.f / (1.f + __expf(-2.f * xv)) - 1.f;
    }

    // ---- x-path table (raw, no exp2-constant folding): tbl = (Wx@emb)[row][d] ----
    for (int i = tid; i < 10240; i += 512) {
        int gi = i & 15, g = gi >> 2, io = gi & 3;
        int qq = (i >> 4) & 3;
        int d  = (i >> 6) % 10;
        int rtw = i / 640;                                   // w*2+rt
        int row = (rtw >> 1) * 32 + (rtw & 1) * 16 + qq * 4 + io;
        float s = 0.f;
        #pragma unroll
        for (int e = 0; e < 6; e++) s += WxT[g][row * 6 + e] * emb[d * 6 + e];
        tblL[rtw * 720 + d * 72 + qq * 16 + gi] = f2b(s);
    }

    // ---- weight quantization: per-row scale, i8 A-frags in registers ----
    // A[m=lane&15 -> row rw+16rt+l][k = 64kt+16q+j], 16 i8 per lane per kt
    int4v wa[4][2][4];
    #pragma unroll
    for (int g = 0; g < 4; g++)
        #pragma unroll
        for (int rt = 0; rt < 2; rt++) {
            const float* Wr = WhT[g] + (rw + 16 * rt + l) * 256 + q * 16;
            float mx = 0.f;
            #pragma unroll
            for (int kt = 0; kt < 4; kt++)
                #pragma unroll
                for (int c4 = 0; c4 < 4; c4++) {
                    float4v v = *(const float4v*)(Wr + kt * 64 + c4 * 4);
                    #pragma unroll
                    for (int j = 0; j < 4; j++) mx = fmaxf(mx, fabsf(v[j]));
                }
            mx = fmaxf(mx, __shfl_xor(mx, 16));
            mx = fmaxf(mx, __shfl_xor(mx, 32));
            mx = fmaxf(mx, 1e-20f);
            if (q == 0) scaleL[g * 256 + rw + 16 * rt + l] = mx;
            float qs = 127.f / mx;
            #pragma unroll
            for (int kt = 0; kt < 4; kt++) {
                int4v f;
                #pragma unroll
                for (int dw = 0; dw < 4; dw++) {
                    float4v v = *(const float4v*)(Wr + kt * 64 + dw * 4);
                    int word = 0;
                    #pragma unroll
                    for (int byt = 0; byt < 4; byt++) {
                        int z = (int)rintf(v[byt] * qs);
                        word |= (z & 255) << (8 * byt);
                    }
                    f[dw] = word;
                }
                wa[g][rt][kt] = f;
            }
        }

    __syncthreads();   // scaleL/tblL/xdig2/hbuf[0]/LUTs visible

    // ---- loop-invariant dequant scales (rows rw+16rt+4q+i) and biases (col l) ----
    float dscl[4][8];
    #pragma unroll
    for (int g = 0; g < 4; g++) {
        const float kk = 1.f / 16129.f;   // 127^2
        #pragma unroll
        for (int rt = 0; rt < 2; rt++)
            #pragma unroll
            for (int i = 0; i < 4; i++)
                dscl[g][rt * 4 + i] = scaleL[g * 256 + rw + 16 * rt + 4 * q + i] * kk;
    }
    float bSc[4];
    bSc[0] = bg[c0 + l]; bSc[1] = bi[c0 + l];
    bSc[2] = bff[c0 + l]; bSc[3] = bo[c0 + l];

    float cs[2][4] = {{0.f, 0.f, 0.f, 0.f}, {0.f, 0.f, 0.f, 0.f}};
    float hl[2][4];   // last-step h (for projection), exact f32

    for (int t = 0; t < 512; t++) {
        const int p = t & 1;
        const char* hbase = (const char*)hbuf[p] + l * 272 + q * 16;
        char*       hdst  = (char*)hbuf[1 - p]  + l * 272 + rw + 4 * q;

        int4v acc[4][2];
        #pragma unroll
        for (int g = 0; g < 4; g++)
            #pragma unroll
            for (int rt = 0; rt < 2; rt++)
                acc[g][rt] = (int4v){0, 0, 0, 0};

        int dg = xdig2[t * 16 + l];
        const short* tp0 = &tblL[(w * 2 + 0) * 720 + dg * 72 + q * 16];
        const short* tp1 = &tblL[(w * 2 + 1) * 720 + dg * 72 + q * 16];
        short8 tv0a = *(const short8*)tp0, tv0b = *(const short8*)(tp0 + 8);
        short8 tv1a = *(const short8*)tp1, tv1b = *(const short8*)(tp1 + 8);

        #pragma unroll
        for (int kt = 0; kt < 4; kt++) {
            int4v hf = *(const int4v*)(hbase + kt * 64);   // B[k=64kt+16q+j][n=col l]
            #pragma unroll
            for (int g = 0; g < 4; g++) {
                acc[g][0] = MFMA_I8(wa[g][0][kt], hf, acc[g][0]);
                acc[g][1] = MFMA_I8(wa[g][1][kt], hf, acc[g][1]);
            }
        }
        // no barrier: writes go to the other h buffer

        // ---- elementwise: thread owns rows rw+16rt+4q+i (i=0..3), col l ----
        #pragma unroll
        for (int rt = 0; rt < 2; rt++) {
            short8 tA = rt ? tv1a : tv0a;   // g0 (i0..3), g1 (i0..3)
            short8 tB = rt ? tv1b : tv0b;   // g2, g3
            int word = 0;
            #pragma unroll
            for (int i = 0; i < 4; i++) {
                float pg = fmaf((float)acc[0][rt][i], dscl[0][rt * 4 + i], b2f(tA[i])     + bSc[0]);
                float pi = fmaf((float)acc[1][rt][i], dscl[1][rt * 4 + i], b2f(tA[4 + i]) + bSc[1]);
                float pf = fmaf((float)acc[2][rt][i], dscl[2][rt * 4 + i], b2f(tB[i])     + bSc[2]);
                float po = fmaf((float)acc[3][rt][i], dscl[3][rt * 4 + i], b2f(tB[4 + i]) + bSc[3]);
                float gg = lutT[lut_idx(pg)];
                float ii = lutS[lut_idx(pi)];
                float ff = lutS[lut_idx(pf)];
                float oo = lutS[lut_idx(po)];
                float c  = fmaf(gg, ii, cs[rt][i] * ff);
                cs[rt][i] = c;
                float th = lutT[lut_idx(c)];
                float hh = th * oo;
                hl[rt][i] = hh;
                int hq = (int)rintf(hh * 127.f);
                word |= (hq & 255) << (8 * i);
            }
            *(int*)(hdst + 16 * rt) = word;
        }
        __syncthreads();   // h_t (other buffer) fully written; h_{t-1} reads all done
    }

    // ---- stage final h (exact f32->bf16) for projection ----
    #pragma unroll
    for (int rt = 0; rt < 2; rt++) {
        short4v hw;
        hw[0] = f2b(hl[rt][0]); hw[1] = f2b(hl[rt][1]);
        hw[2] = f2b(hl[rt][2]); hw[3] = f2b(hl[rt][3]);
        *(short4v*)&hfin[l * 264 + rw + 16 * rt + 4 * q] = hw;
    }
    __syncthreads();

    // ---- projection: out[c0+col][cls] = Wp[cls] . h_final + bp[cls] ----
    if (tid < 160) {
        int col = tid / 10, cls = tid - col * 10;
        const short* hcol = &hfin[col * 264];
        const float* wrow = Wp + cls * 256;
        float s = 0.f;
        #pragma unroll 8
        for (int k = 0; k < 256; k++) s += b2f(hcol[k]) * wrow[k];
        out[(c0 + col) * 10 + cls] = s + bp[cls];
    }
}

extern "C" void kernel_launch(void* const* d_in, const int* in_sizes, int n_in,
                              void* d_out, int out_size, void* d_ws, size_t ws_size,
                              hipStream_t stream) {
    const int*   x   = (const int*)d_in[0];
    const float* emb = (const float*)d_in[1];
    const float* Wxg = (const float*)d_in[2];
    const float* Whg = (const float*)d_in[3];
    const float* bg  = (const float*)d_in[4];
    const float* Wxi = (const float*)d_in[5];
    const float* Whi = (const float*)d_in[6];
    const float* bi  = (const float*)d_in[7];
    const float* Wxf = (const float*)d_in[8];
    const float* Whf = (const float*)d_in[9];
    const float* bff = (const float*)d_in[10];
    const float* Wxo = (const float*)d_in[11];
    const float* Who = (const float*)d_in[12];
    const float* bo  = (const float*)d_in[13];
    const float* Wp  = (const float*)d_in[14];
    const float* bp  = (const float*)d_in[15];

    hipLaunchKernelGGL(lstm_i8, dim3(16), dim3(512), 0, stream,
                       x, emb, Wxg, Whg, bg, Wxi, Whi, bi, Wxf, Whf, bff,
                       Wxo, Who, bo, Wp, bp, (float*)d_out);
}